// Round 1
// baseline (628.934 us; speedup 1.0000x reference)
//
#include <hip/hip_runtime.h>
#include <math.h>

// Problem constants (fixed by reference setup_inputs)
#define B_ 16
#define C_ 512
#define N_ 4096   // 64*64
#define K_ 64

// Workspace layout (float offsets). Total = 655360 + 524288 floats = ~4.7 MB.
#define OFF_INVS2T  0         // [C][K]  1/sigma^2, c-major (k contiguous)
#define OFF_AS2M2T  32768     // [C][K]  -2*anchor/sigma^2
#define OFF_INVSIG  65536     // [K][C]  1/sigma
#define OFF_CONST   98304     // [K]     sum_c anchor^2/sigma^2
#define OFF_WSUM    98368     // [B][K]
#define OFF_GSUM    99392     // [B]
#define OFF_WX      131072    // [B][K][C]  aggregation accumulator (atomic)
#define OFF_NODES   655360    // [B][K][C]  intra-normalized nodes

// ---------------------------------------------------------------- kernel 1
// Per-k parameter prep + zero the atomic accumulators.
__global__ void k_prep(const float* __restrict__ anchor,
                       const float* __restrict__ sraw,
                       float* __restrict__ invs2t,
                       float* __restrict__ as2m2t,
                       float* __restrict__ invsig,
                       float* __restrict__ constk,
                       float* __restrict__ wsum,
                       float* __restrict__ gsum,
                       float* __restrict__ wx) {
  const int k = blockIdx.x;
  const int tid = threadIdx.x;
  float partial = 0.f;
#pragma unroll
  for (int r = 0; r < 2; r++) {
    int c = r * 256 + tid;
    float a = anchor[k * C_ + c];
    float s = 1.f / (1.f + __expf(-sraw[k * C_ + c]));   // sigmoid
    float is = 1.f / s;
    float is2 = is * is;
    invs2t[c * K_ + k] = is2;
    as2m2t[c * K_ + k] = -2.f * a * is2;
    invsig[k * C_ + c] = is;
    partial = fmaf(a * a, is2, partial);
  }
  float v = partial;
#pragma unroll
  for (int off = 32; off; off >>= 1) v += __shfl_down(v, off);
  __shared__ float red[4];
  if ((tid & 63) == 0) red[tid >> 6] = v;
  __syncthreads();
  if (tid == 0) constk[k] = red[0] + red[1] + red[2] + red[3];
  // zero atomic accumulators (kernel runs before users, stream-ordered)
  for (int i = tid; i < 8192; i += 256) wx[(size_t)k * 8192 + i] = 0.f;
  if (k == 0) {
    for (int i = tid; i < B_ * K_; i += 256) wsum[i] = 0.f;
    if (tid < B_) gsum[tid] = 0.f;
  }
}

// ---------------------------------------------------------------- kernel 2
// Distance + softmax over K + w_sum atomics.
// grid (N/128, B), block 256. Thread: one n, 32-k half (wave-uniform).
__global__ void k_dist(const float* __restrict__ x,
                       const float* __restrict__ invs2t,
                       const float* __restrict__ as2m2t,
                       const float* __restrict__ constk,
                       float* __restrict__ soft,
                       float* __restrict__ wsum) {
  const int b = blockIdx.y;
  const int tid = threadIdx.x;
  const int nl = tid & 127;
  const int n = blockIdx.x * 128 + nl;
  // k-half: waves 0,1 -> k 0..31 ; waves 2,3 -> k 32..63 (wave-uniform)
  const int kbase = __builtin_amdgcn_readfirstlane((tid >> 7) << 5);
  const int half = kbase >> 5;
  const float* xb = x + (size_t)b * ((size_t)C_ * N_) + n;

  float acc[32];
#pragma unroll
  for (int j = 0; j < 32; j++) acc[j] = 0.f;

  for (int c = 0; c < C_; c++) {
    float xv = xb[(size_t)c * N_];          // coalesced per wave
    float x2 = xv * xv;
    const float* pi = invs2t + c * K_ + kbase;   // uniform addr -> s_load
    const float* pa = as2m2t + c * K_ + kbase;
#pragma unroll
    for (int j = 0; j < 32; j++) {
      acc[j] = fmaf(x2, pi[j], acc[j]);
      acc[j] = fmaf(xv, pa[j], acc[j]);
    }
  }

  const float* ck = constk + kbase;
  float m = -3.4e38f;
#pragma unroll
  for (int j = 0; j < 32; j++) {
    acc[j] = -0.5f * (acc[j] + ck[j]);      // logits
    m = fmaxf(m, acc[j]);
  }
  // exchange max with the other k-half
  __shared__ float red[2][128];
  red[half][nl] = m;
  __syncthreads();
  m = fmaxf(m, red[half ^ 1][nl]);
  float s = 0.f;
#pragma unroll
  for (int j = 0; j < 32; j++) {
    float e = __expf(acc[j] - m);
    acc[j] = e;
    s += e;
  }
  __syncthreads();
  red[half][nl] = s;
  __syncthreads();
  s += red[half ^ 1][nl];
  float inv = 1.f / s;

  float* op = soft + ((size_t)(b * K_ + kbase)) * N_ + n;
#pragma unroll
  for (int j = 0; j < 32; j++) {
    float w = acc[j] * inv;
    acc[j] = w;
    op[(size_t)j * N_] = w;                 // coalesced per k row
  }
  // w_sum: every lane in this wave shares kbase -> shuffle-reduce over n
#pragma unroll
  for (int j = 0; j < 32; j++) {
    float v = acc[j];
#pragma unroll
    for (int off = 32; off; off >>= 1) v += __shfl_down(v, off);
    if ((tid & 63) == 0) atomicAdd(&wsum[b * K_ + kbase + j], v);
  }
}

// ---------------------------------------------------------------- kernel 3
// Aggregation GEMM: wx[b,k,c] += sum_n soft[b,k,n] * x[b,c,n]
// grid (C/128, 8 n-splits, B), block 256. Thread tile 4k x 8c.
__global__ void k_agg(const float* __restrict__ x,
                      const float* __restrict__ soft,
                      float* __restrict__ wx) {
  const int ct = blockIdx.x;        // c0 = ct*128
  const int nt = blockIdx.y;        // n range [nt*512, nt*512+512)
  const int b = blockIdx.z;
  const int tid = threadIdx.x;
  const int tk = tid >> 4;          // 0..15 -> k = 4*tk
  const int tc = tid & 15;          // 0..15 -> c = 8*tc
  // n-major staged tiles; pads keep rows 16B-aligned for ds_read_b128
  __shared__ float wsh[32][68];
  __shared__ float xsh[32][132];
  float acc[4][8];
#pragma unroll
  for (int i = 0; i < 4; i++)
#pragma unroll
    for (int j = 0; j < 8; j++) acc[i][j] = 0.f;

  const float* wb = soft + (size_t)b * K_ * N_ + nt * 512;
  const float* xb = x + ((size_t)b * C_ + ct * 128) * (size_t)N_ + nt * 512;
  const int ni = tid & 31, rr = tid >> 5;   // stage: 32 n x (8|16) rows

  for (int n0 = 0; n0 < 512; n0 += 32) {
#pragma unroll
    for (int r = 0; r < 8; r++)
      wsh[ni][rr + r * 8] = wb[(size_t)(rr + r * 8) * N_ + n0 + ni];
#pragma unroll
    for (int r = 0; r < 16; r++)
      xsh[ni][rr + r * 8] = xb[(size_t)(rr + r * 8) * N_ + n0 + ni];
    __syncthreads();
#pragma unroll 4
    for (int n = 0; n < 32; n++) {
      float wv[4], xv[8];
#pragma unroll
      for (int i = 0; i < 4; i++) wv[i] = wsh[n][tk * 4 + i];
#pragma unroll
      for (int j = 0; j < 8; j++) xv[j] = xsh[n][tc * 8 + j];
#pragma unroll
      for (int i = 0; i < 4; i++)
#pragma unroll
        for (int j = 0; j < 8; j++)
          acc[i][j] = fmaf(wv[i], xv[j], acc[i][j]);
    }
    __syncthreads();
  }
  float* wxp = wx + ((size_t)b * K_) * C_ + ct * 128;
#pragma unroll
  for (int i = 0; i < 4; i++)
#pragma unroll
    for (int j = 0; j < 8; j++)
      atomicAdd(&wxp[(size_t)(tk * 4 + i) * C_ + tc * 8 + j], acc[i][j]);
}

// ---------------------------------------------------------------- kernel 4
// nodes = (wx - wsum*anchor)/sigma/(wsum+eps); intra L2-norm; global sumsq.
// grid (K, B), block 128.
__global__ void k_nodes(const float* __restrict__ wx,
                        const float* __restrict__ wsum,
                        const float* __restrict__ anchor,
                        const float* __restrict__ invsig,
                        float* __restrict__ nodes,
                        float* __restrict__ gsum) {
  const int k = blockIdx.x, b = blockIdx.y;
  const int tid = threadIdx.x;
  float wsv = wsum[b * K_ + k];
  float winv = 1.f / (wsv + 1e-9f);
  float vals[4];
  float local = 0.f;
#pragma unroll
  for (int r = 0; r < 4; r++) {
    int c = r * 128 + tid;
    float w = wx[((size_t)(b * K_) + k) * C_ + c];
    float v = (w - wsv * anchor[k * C_ + c]) * invsig[k * C_ + c] * winv;
    vals[r] = v;
    local = fmaf(v, v, local);
  }
  float v = local;
#pragma unroll
  for (int off = 32; off; off >>= 1) v += __shfl_down(v, off);
  __shared__ float red[2];
  if ((tid & 63) == 0) red[tid >> 6] = v;
  __syncthreads();
  float sumsq = red[0] + red[1];
  float norm = sqrtf(sumsq);
  float scale = 1.f / fmaxf(norm, 1e-12f);
#pragma unroll
  for (int r = 0; r < 4; r++) {
    int c = r * 128 + tid;
    nodes[((size_t)(b * K_) + k) * C_ + c] = vals[r] * scale;
  }
  if (tid == 0) atomicAdd(&gsum[b], sumsq * scale * scale);
}

// ---------------------------------------------------------------- kernel 5
// Global L2 scale + write out0 ([B][K*C] flat == reference reshape(B,C,K)).
__global__ void k_final(const float* __restrict__ nodes,
                        const float* __restrict__ gsum,
                        float* __restrict__ out0) {
  for (int i = blockIdx.x * 256 + threadIdx.x; i < B_ * K_ * C_;
       i += gridDim.x * 256) {
    int b = i >> 15;  // K_*C_ = 32768
    out0[i] = nodes[i] * (1.f / fmaxf(sqrtf(gsum[b]), 1e-12f));
  }
}

// ---------------------------------------------------------------- launch
extern "C" void kernel_launch(void* const* d_in, const int* in_sizes, int n_in,
                              void* d_out, int out_size, void* d_ws, size_t ws_size,
                              hipStream_t stream) {
  const float* x = (const float*)d_in[0];       // [B,C,H,W]
  const float* anchor = (const float*)d_in[1];  // [K,C]
  const float* sraw = (const float*)d_in[2];    // [K,C]
  float* out0 = (float*)d_out;                          // [B,C,K] flat
  float* soft = out0 + (size_t)B_ * C_ * K_;            // [B,K,N]
  float* ws = (float*)d_ws;                             // needs ~4.7 MB

  float* invs2t = ws + OFF_INVS2T;
  float* as2m2t = ws + OFF_AS2M2T;
  float* invsig = ws + OFF_INVSIG;
  float* constk = ws + OFF_CONST;
  float* wsum = ws + OFF_WSUM;
  float* gsum = ws + OFF_GSUM;
  float* wx = ws + OFF_WX;
  float* nodes = ws + OFF_NODES;

  k_prep<<<K_, 256, 0, stream>>>(anchor, sraw, invs2t, as2m2t, invsig, constk,
                                 wsum, gsum, wx);
  k_dist<<<dim3(N_ / 128, B_), 256, 0, stream>>>(x, invs2t, as2m2t, constk,
                                                 soft, wsum);
  k_agg<<<dim3(C_ / 128, 8, B_), 256, 0, stream>>>(x, soft, wx);
  k_nodes<<<dim3(K_, B_), 128, 0, stream>>>(wx, wsum, anchor, invsig, nodes,
                                            gsum);
  k_final<<<512, 256, 0, stream>>>(nodes, gsum, out0);
}